// Round 16
// baseline (1377.239 us; speedup 1.0000x reference)
//
#include <hip/hip_runtime.h>

#define HW 200704          // 448*448
#define WIMG 448
#define VPLANE 229376      // 4096 windows * 56 padded pixels (u16 elements)

typedef __attribute__((ext_vector_type(4))) unsigned int u32x4;
typedef __attribute__((ext_vector_type(4))) float f32x4;
typedef __attribute__((ext_vector_type(8))) short s16x8;

static __device__ __forceinline__ unsigned short f2bf(float f) {
    union { float f; unsigned int u; } v; v.f = f;
    unsigned int u = v.u;
    unsigned int r = u + 0x7FFFu + ((u >> 16) & 1u);   // RNE
    return (unsigned short)(r >> 16);
}
static __device__ __forceinline__ float bf2f(unsigned short s) {
    union { unsigned int u; float f; } v; v.u = ((unsigned int)s) << 16;
    return v.f;
}

// ---------------------------------------------------------------------------
// K-1: weight convert fp32 [ocu][180] -> bf16 [octot][192] (pads zeroed)
// ---------------------------------------------------------------------------
__global__ __launch_bounds__(256) void wconv_kernel(
    const float* __restrict__ src, unsigned short* __restrict__ dst,
    int ocu, int octot)
{
    int idx = blockIdx.x * 256 + threadIdx.x;
    if (idx >= octot * 24) return;
    int row = idx / 24, ch = idx - row * 24;
    unsigned short u[8];
#pragma unroll
    for (int e = 0; e < 8; ++e) {
        int k = ch * 8 + e;
        u[e] = (row < ocu && k < 180) ? f2bf(src[row * 180 + k]) : (unsigned short)0;
    }
    *(u32x4*)(dst + row * 192 + ch * 8) = *(const u32x4*)u;
}

// ---------------------------------------------------------------------------
// K0: transpose+cast  x fp32 [180][HW] -> xT bf16 [HW][192] (one batch)
// ---------------------------------------------------------------------------
__global__ __launch_bounds__(256) void transpose_cast_kernel(
    const float* __restrict__ x, unsigned short* __restrict__ xT)
{
    const int p0 = blockIdx.x * 64;
    const int tid = threadIdx.x;
    const int pl = tid & 63;

    __shared__ float T[180 * 65];

    for (int ic = tid >> 6; ic < 180; ic += 4)
        T[ic * 65 + pl] = x[(size_t)ic * HW + p0 + pl];
    __syncthreads();

    const int cg = tid >> 6;
    unsigned short* drow = xT + ((size_t)p0 + pl) * 192;
#pragma unroll
    for (int i = 0; i < 6; ++i) {
        int k0 = (cg * 6 + i) * 8;
        unsigned short u[8];
#pragma unroll
        for (int e = 0; e < 8; ++e)
            u[e] = (k0 + e < 180) ? f2bf(T[(k0 + e) * 65 + pl]) : (unsigned short)0;
        *(u32x4*)(drow + k0) = *(const u32x4*)u;
    }
}

// ---------------------------------------------------------------------------
// K1: qkv GEMM via MFMA (one batch). 64 oc x 256 px per block, 256 threads.
// LDS-FREE: B-fragments loaded directly from xT (16 rows x 64B lines, fully
// consumed; L2-served via XCD swizzle reuse), weights direct from wqb.
// No barriers -> pure load/MFMA interleave, occupancy VGPR-bound.
// ---------------------------------------------------------------------------
__global__ __launch_bounds__(256) void gemm_qkv_kernel(
    const unsigned short* __restrict__ xT, const unsigned short* __restrict__ wqb,
    unsigned short* __restrict__ A)
{
    const int d    = blockIdx.x;               // 0..7055
    const int orig = (d & 7) * 882 + (d >> 3); // bijective (7056 = 8*882)
    const int pt   = orig / 9;
    const int ocb  = (orig - pt * 9) * 64;
    const int pix0 = pt * 256;
    const int tid  = threadIdx.x;
    const int l    = tid & 63;
    const int q    = tid >> 6;     // px quarter (64 px)
    const int r15  = l & 15;
    const int g4   = l >> 4;

    f32x4 acc[4][4];   // [nt: px frag][mi: oc frag], px on reg dim
#pragma unroll
    for (int nt = 0; nt < 4; ++nt)
#pragma unroll
        for (int mi = 0; mi < 4; ++mi) acc[nt][mi] = (f32x4){0.f, 0.f, 0.f, 0.f};

    const unsigned short* wrow = wqb + (size_t)(ocb + r15) * 192 + g4 * 8;
    const unsigned short* xrow = xT + ((size_t)pix0 + q * 64 + r15) * 192 + g4 * 8;

    for (int c = 0; c < 3; ++c) {
#pragma unroll
        for (int kk = 0; kk < 2; ++kk) {
            const int ko = c * 64 + kk * 32;
            s16x8 aX[4], bW[4];
#pragma unroll
            for (int nt = 0; nt < 4; ++nt)
                aX[nt] = __builtin_bit_cast(s16x8, *(const u32x4*)(
                    xrow + (size_t)(nt * 16) * 192 + ko));
#pragma unroll
            for (int mi = 0; mi < 4; ++mi)
                bW[mi] = __builtin_bit_cast(s16x8, *(const u32x4*)(
                    wrow + (size_t)(mi * 16) * 192 + ko));
#pragma unroll
            for (int nt = 0; nt < 4; ++nt)
#pragma unroll
                for (int mi = 0; mi < 4; ++mi)
                    acc[nt][mi] = __builtin_amdgcn_mfma_f32_16x16x32_bf16(
                        aX[nt], bW[mi], acc[nt][mi], 0, 0, 0);
        }
    }

#pragma unroll
    for (int mi = 0; mi < 4; ++mi) {
        int oc = ocb + mi * 16 + r15;
        if (oc < 540) {
            unsigned short* orow = A + (size_t)oc * HW + pix0 + q * 64 + g4 * 4;
#pragma unroll
            for (int nt = 0; nt < 4; ++nt) {
                uint2 v;
                v.x = (unsigned int)f2bf(acc[nt][mi][0]) |
                      ((unsigned int)f2bf(acc[nt][mi][1]) << 16);
                v.y = (unsigned int)f2bf(acc[nt][mi][2]) |
                      ((unsigned int)f2bf(acc[nt][mi][3]) << 16);
                *(uint2*)(orow + nt * 16) = v;
            }
        }
    }
}

// ---------------------------------------------------------------------------
// K2: depthwise 3x3 (SAME) + window rearrange (one batch).  [R14 version]
// ---------------------------------------------------------------------------
__global__ __launch_bounds__(256) void dw_kernel(
    const unsigned short* __restrict__ A, const float* __restrict__ wdw,
    unsigned short* __restrict__ Bw)
{
    const int wrow = blockIdx.x;   // 0..63
    const int c    = blockIdx.y;   // 0..539
    const int tid  = threadIdx.x;

    const int part = c / 180;
    const int rem  = c - part * 180;
    const int head = rem / 30;
    const int dc   = rem - head * 30;

    __shared__ __align__(8) float Ls[9 * 454];   // (r, ximg) at Ls[r*454 + 2 + ximg]

    float w9[9];
#pragma unroll
    for (int i = 0; i < 9; ++i) w9[i] = wdw[c * 9 + i];

    const int y0 = wrow * 7;
    const unsigned int* Ac32 = (const unsigned int*)(A + (size_t)c * HW);
    for (int idx = tid; idx < 2016; idx += 256) {
        int r  = idx / 224;
        int c2 = idx - r * 224;
        int y  = y0 + r - 1;
        unsigned int v = ((unsigned)y < 448u) ? Ac32[y * 224 + c2] : 0u;
        float2 f2;
        f2.x = bf2f((unsigned short)(v & 0xffffu));
        f2.y = bf2f((unsigned short)(v >> 16));
        *(float2*)(Ls + r * 454 + 2 + 2 * c2) = f2;
    }
    if (tid < 18) {
        int r = tid >> 1;
        Ls[r * 454 + ((tid & 1) ? 450 : 1)] = 0.f;
    }
    __syncthreads();

    unsigned short* dstb = Bw +
        ((size_t)(head * 3 + part) * 30 + dc) * VPLANE + (size_t)wrow * 3584;

    for (int idx = tid; idx < 448; idx += 256) {
        int wo = idx / 7;
        int pp = idx - wo * 7;
        dstb[wo * 56 + 49 + pp] = 0;
    }

    if (tid < 224) {
        const int wp = tid / 7;
        const int ph = tid - wp * 7;

        float acc[14];
#pragma unroll
        for (int j = 0; j < 14; ++j) acc[j] = 0.f;

#pragma unroll
        for (int k = 0; k < 3; ++k) {
            const float2* Lp = (const float2*)(Ls + (ph + k) * 454 + wp * 14);
            float v[18];
#pragma unroll
            for (int t = 0; t < 9; ++t) {
                float2 f2 = Lp[t];
                v[2 * t]     = f2.x;
                v[2 * t + 1] = f2.y;
            }
            float wk0 = w9[k * 3], wk1 = w9[k * 3 + 1], wk2 = w9[k * 3 + 2];
#pragma unroll
            for (int j = 0; j < 14; ++j)
                acc[j] += wk0 * v[j + 1] + wk1 * v[j + 2] + wk2 * v[j + 3];
        }

        unsigned short* o0 = dstb + (2 * wp) * 56 + ph * 7;
        unsigned short* o1 = o0 + 56;
#pragma unroll
        for (int t = 0; t < 7; ++t) {
            o0[t] = f2bf(acc[t]);
            o1[t] = f2bf(acc[7 + t]);
        }
    }
}

// ---------------------------------------------------------------------------
// K3: channel attention (one batch). Block = 4 consecutive windows of one head,
// one wave each. Vectorized b128 staging for Q/K; per-element transpose for V.
// Out: Cwt [win][49][192] bf16 (ch 180..191 zeroed by head==5)
// ---------------------------------------------------------------------------
__global__ __launch_bounds__(256) void attn2_kernel(
    const unsigned short* __restrict__ Bw,
    const float* __restrict__ temperature,
    unsigned short* __restrict__ Cwt)
{
    __shared__ __align__(16) unsigned short lds[4][6144];
    __shared__ float invs[4][64];

    const int w    = threadIdx.x >> 6;
    const int l    = threadIdx.x & 63;
    const int wg   = blockIdx.x;
    const int head = blockIdx.y;
    const int win  = wg * 4 + w;
    const float temp = temperature[head];
    unsigned short* U = lds[w];
    float* inv = invs[w];
    const int r15 = l & 15;
    const int g4  = l >> 4;

    // ---- stage Q/K: 8 b128 per lane (rows>=30 and chunk 7 -> zeros) ----
    {
        const unsigned short* plane0 =
            Bw + (size_t)(head * 3) * 30 * VPLANE + (size_t)win * 56;
#pragma unroll
        for (int i = 0; i < 8; ++i) {
            int part = i >> 2;
            int row  = ((i & 3) << 3) | (l >> 3);   // 0..31
            int c    = l & 7;
            u32x4 v = {0u, 0u, 0u, 0u};
            if (row < 30 && c < 7)
                v = *(const u32x4*)(plane0 + (size_t)(part * 30 + row) * VPLANE + c * 8);
            *(u32x4*)(U + part * 2048 + row * 64 + ((c ^ (row & 7)) << 3)) = v;
        }
    }
    // ---- stage V transposed into Vt [p][32] (swizzled), zero cols 30/31 ----
    {
        const unsigned short* vplane =
            Bw + (size_t)(head * 3 + 2) * 30 * VPLANE + (size_t)win * 56;
        for (int j = 0; j < 23; ++j) {
            int idx = j * 64 + l;
            if (idx < 1470) {
                int dc = idx / 49;
                int p  = idx - dc * 49;
                unsigned short val = vplane[(size_t)dc * VPLANE + p];
                int col = (((dc >> 3) ^ (p & 3)) << 3) | (dc & 7);
                U[4096 + p * 32 + col] = val;
            }
        }
        int c30 = ((3 ^ (l & 3)) << 3) | 6;         // dc=30 slot for p=l
        U[4096 + l * 32 + c30]     = 0;
        U[4096 + l * 32 + c30 + 1] = 0;             // dc=31
    }
    __syncthreads();

    s16x8 aQ[2][2], bK[2][2];
#pragma unroll
    for (int mi = 0; mi < 2; ++mi)
#pragma unroll
        for (int kk = 0; kk < 2; ++kk) {
            int r  = mi * 16 + r15;
            int gk = kk * 4 + g4;
            int so = ((gk ^ (r & 7)) << 3);
            aQ[mi][kk] = __builtin_bit_cast(s16x8, *(const u32x4*)(U + r * 64 + so));
            bK[mi][kk] = __builtin_bit_cast(s16x8, *(const u32x4*)(U + 2048 + r * 64 + so));
        }

    f32x4 s[2][2], dq[2], dk[2];
#pragma unroll
    for (int mi = 0; mi < 2; ++mi) {
        dq[mi] = (f32x4){0.f, 0.f, 0.f, 0.f};
        dk[mi] = (f32x4){0.f, 0.f, 0.f, 0.f};
#pragma unroll
        for (int nj = 0; nj < 2; ++nj) s[mi][nj] = (f32x4){0.f, 0.f, 0.f, 0.f};
    }

#pragma unroll
    for (int kk = 0; kk < 2; ++kk) {
#pragma unroll
        for (int mi = 0; mi < 2; ++mi) {
#pragma unroll
            for (int nj = 0; nj < 2; ++nj)
                s[mi][nj] = __builtin_amdgcn_mfma_f32_16x16x32_bf16(
                    aQ[mi][kk], bK[nj][kk], s[mi][nj], 0, 0, 0);
            dq[mi] = __builtin_amdgcn_mfma_f32_16x16x32_bf16(
                aQ[mi][kk], aQ[mi][kk], dq[mi], 0, 0, 0);
            dk[mi] = __builtin_amdgcn_mfma_f32_16x16x32_bf16(
                bK[mi][kk], bK[mi][kk], dk[mi], 0, 0, 0);
        }
    }

#pragma unroll
    for (int mi = 0; mi < 2; ++mi)
#pragma unroll
        for (int reg = 0; reg < 4; ++reg) {
            int row = g4 * 4 + reg;
            if (row == r15) {
                inv[mi * 16 + row]      = 1.f / fmaxf(sqrtf(dq[mi][reg]), 1e-12f);
                inv[32 + mi * 16 + row] = 1.f / fmaxf(sqrtf(dk[mi][reg]), 1e-12f);
            }
        }
    __syncthreads();

    float pr[2][2][4];
    float cinvk0 = inv[32 + r15];
    float cinvk1 = inv[32 + 16 + r15];
#pragma unroll
    for (int mi = 0; mi < 2; ++mi)
#pragma unroll
        for (int reg = 0; reg < 4; ++reg) {
            float qi = inv[mi * 16 + g4 * 4 + reg];
            float v0 = s[mi][0][reg] * qi * cinvk0 * temp;
            float v1 = s[mi][1][reg] * qi * cinvk1 * temp;
            if (16 + r15 >= 30) v1 = -1e30f;
            float m = fmaxf(v0, v1);
#pragma unroll
            for (int off = 1; off < 16; off <<= 1) m = fmaxf(m, __shfl_xor(m, off));
            float e0 = __expf(v0 - m);
            float e1 = __expf(v1 - m);
            float sum = e0 + e1;
#pragma unroll
            for (int off = 1; off < 16; off <<= 1) sum += __shfl_xor(sum, off);
            float rs = 1.f / sum;
            pr[mi][0][reg] = e0 * rs;
            pr[mi][1][reg] = e1 * rs;
        }

#pragma unroll
    for (int mi = 0; mi < 2; ++mi)
#pragma unroll
        for (int nj = 0; nj < 2; ++nj)
#pragma unroll
            for (int reg = 0; reg < 4; ++reg) {
                int row = mi * 16 + g4 * 4 + reg;
                int col = nj * 16 + r15;
                int scol = (((col >> 3) ^ (row & 3)) << 3) | (col & 7);
                U[row * 32 + scol] = f2bf(pr[mi][nj][reg]);
            }
    __syncthreads();

    s16x8 aP[2], bV[4];
#pragma unroll
    for (int mi = 0; mi < 2; ++mi) {
        int i = mi * 16 + r15;
        aP[mi] = __builtin_bit_cast(s16x8,
                 *(const u32x4*)(U + i * 32 + ((g4 ^ (i & 3)) << 3)));
    }
#pragma unroll
    for (int nt = 0; nt < 4; ++nt) {
        int p = nt * 16 + r15;
        bV[nt] = __builtin_bit_cast(s16x8,
                 *(const u32x4*)(U + 4096 + p * 32 + ((g4 ^ (p & 3)) << 3)));
    }
    f32x4 o[2][4];
#pragma unroll
    for (int mi = 0; mi < 2; ++mi)
#pragma unroll
        for (int nt = 0; nt < 4; ++nt) {
            o[mi][nt] = (f32x4){0.f, 0.f, 0.f, 0.f};
            o[mi][nt] = __builtin_amdgcn_mfma_f32_16x16x32_bf16(
                aP[mi], bV[nt], o[mi][nt], 0, 0, 0);
        }

    unsigned short* dst = Cwt + ((size_t)win * 49) * 192 + head * 30;
#pragma unroll
    for (int mi = 0; mi < 2; ++mi) {
        int ch0 = mi * 16 + g4 * 4;
#pragma unroll
        for (int nt = 0; nt < 4; ++nt) {
            int p = nt * 16 + r15;
            if (p < 49) {
                unsigned int lo = (unsigned int)f2bf(o[mi][nt][0]) |
                                  ((unsigned int)f2bf(o[mi][nt][1]) << 16);
                *(unsigned int*)(dst + (size_t)p * 192 + ch0) = lo;
                if (ch0 + 2 < 30) {
                    unsigned int hi = (unsigned int)f2bf(o[mi][nt][2]) |
                                      ((unsigned int)f2bf(o[mi][nt][3]) << 16);
                    *(unsigned int*)(dst + (size_t)p * 192 + ch0 + 2) = hi;
                }
            }
        }
    }
    if (head == 5 && g4 == 0) {
        unsigned short* zrow = Cwt + ((size_t)win * 49) * 192 + 180;
#pragma unroll
        for (int nt = 0; nt < 4; ++nt) {
            int p = nt * 16 + r15;
            if (p < 49) {
                *(unsigned int*)(zrow + (size_t)p * 192 + 0) = 0u;
                *(unsigned int*)(zrow + (size_t)p * 192 + 2) = 0u;
                *(unsigned int*)(zrow + (size_t)p * 192 + 4) = 0u;
            }
        }
    }
}

// ---------------------------------------------------------------------------
// K4: proj GEMM via MFMA (one batch). LDS-FREE (same pattern as K1).
// ---------------------------------------------------------------------------
__global__ __launch_bounds__(256) void gemm_proj_kernel(
    const unsigned short* __restrict__ Cwt, const unsigned short* __restrict__ wpb,
    float* __restrict__ out)
{
    const int d    = blockIdx.x;                 // 0..2351
    const int orig = (d & 7) * 294 + (d >> 3);   // bijective (2352 = 8*294)
    const int pt   = orig / 3;
    const int ocb  = (orig - pt * 3) * 64;
    const int pix0 = pt * 256;
    const int tid  = threadIdx.x;
    const int l    = tid & 63;
    const int q    = tid >> 6;     // px quarter (64 px)
    const int r15  = l & 15;
    const int g4   = l >> 4;

    f32x4 acc[4][4];   // [mi: oc frag][nt: px frag], D col = px
#pragma unroll
    for (int mi = 0; mi < 4; ++mi)
#pragma unroll
        for (int nt = 0; nt < 4; ++nt) acc[mi][nt] = (f32x4){0.f, 0.f, 0.f, 0.f};

    const unsigned short* wrow = wpb + (size_t)(ocb + r15) * 192 + g4 * 8;
    const unsigned short* xrow = Cwt + ((size_t)pix0 + q * 64 + r15) * 192 + g4 * 8;

    for (int c = 0; c < 3; ++c) {
#pragma unroll
        for (int kk = 0; kk < 2; ++kk) {
            const int ko = c * 64 + kk * 32;
            s16x8 aW[4], bX[4];
#pragma unroll
            for (int mi = 0; mi < 4; ++mi)
                aW[mi] = __builtin_bit_cast(s16x8, *(const u32x4*)(
                    wrow + (size_t)(mi * 16) * 192 + ko));
#pragma unroll
            for (int nt = 0; nt < 4; ++nt)
                bX[nt] = __builtin_bit_cast(s16x8, *(const u32x4*)(
                    xrow + (size_t)(nt * 16) * 192 + ko));
#pragma unroll
            for (int mi = 0; mi < 4; ++mi)
#pragma unroll
                for (int nt = 0; nt < 4; ++nt)
                    acc[mi][nt] = __builtin_amdgcn_mfma_f32_16x16x32_bf16(
                        aW[mi], bX[nt], acc[mi][nt], 0, 0, 0);
        }
    }

    int poff[4];
#pragma unroll
    for (int nt = 0; nt < 4; ++nt) {
        int P = pix0 + q * 64 + nt * 16 + r15;
        int win = P / 49, p = P - win * 49;
        int ph = p / 7, pw2 = p - ph * 7;
        poff[nt] = ((win >> 6) * 7 + ph) * WIMG + (win & 63) * 7 + pw2;
    }
#pragma unroll
    for (int mi = 0; mi < 4; ++mi) {
#pragma unroll
        for (int reg = 0; reg < 4; ++reg) {
            int oc = ocb + mi * 16 + g4 * 4 + reg;
            if (oc < 180) {
#pragma unroll
                for (int nt = 0; nt < 4; ++nt)
                    out[(size_t)oc * HW + poff[nt]] = acc[mi][nt][reg];
            }
        }
    }
}

extern "C" void kernel_launch(void* const* d_in, const int* in_sizes, int n_in,
                              void* d_out, int out_size, void* d_ws, size_t ws_size,
                              hipStream_t stream) {
    const float* x           = (const float*)d_in[0];
    const float* temperature = (const float*)d_in[1];
    const float* w_qkv       = (const float*)d_in[2];
    const float* w_dw        = (const float*)d_in[3];
    const float* w_proj      = (const float*)d_in[4];
    float* out = (float*)d_out;

    // per-batch buffers (reused for b=0,1):
    // xT  @ 0          :  77,070,336 B
    // A   @ 77070336   : 216,760,320 B
    // Bw  @ 293830656  : 247,726,080 B
    // Cwt @ 541556736  :  77,070,336 B
    // wqb @ 618627072  :     221,184 B
    // wpb @ 618848256  :      73,728 B
    if (ws_size < 618921984ull) return;
    unsigned short* xT  = (unsigned short*)d_ws;
    unsigned short* A   = (unsigned short*)((char*)d_ws + 77070336ull);
    unsigned short* Bw  = (unsigned short*)((char*)d_ws + 293830656ull);
    unsigned short* Cwt = (unsigned short*)((char*)d_ws + 541556736ull);
    unsigned short* wqb = (unsigned short*)((char*)d_ws + 618627072ull);
    unsigned short* wpb = (unsigned short*)((char*)d_ws + 618848256ull);

    wconv_kernel<<<dim3(54), 256, 0, stream>>>(w_qkv, wqb, 540, 576);
    wconv_kernel<<<dim3(18), 256, 0, stream>>>(w_proj, wpb, 180, 192);

    for (int b = 0; b < 2; ++b) {
        const float* xb = x + (size_t)b * 180 * HW;
        float* ob = out + (size_t)b * 180 * HW;
        transpose_cast_kernel<<<dim3(HW / 64), 256, 0, stream>>>(xb, xT);
        gemm_qkv_kernel<<<dim3(7056), 256, 0, stream>>>(xT, wqb, A);
        dw_kernel<<<dim3(64, 540), 256, 0, stream>>>(A, w_dw, Bw);
        attn2_kernel<<<dim3(1024, 6), 256, 0, stream>>>(Bw, temperature, Cwt);
        gemm_proj_kernel<<<dim3(2352), 256, 0, stream>>>(Cwt, wpb, ob);
    }
}

// Round 17
// 1264.013 us; speedup vs baseline: 1.0896x; 1.0896x over previous
//
#include <hip/hip_runtime.h>

#define HW 200704          // 448*448
#define WIMG 448
#define VPLANE 229376      // 4096 windows * 56 padded pixels (u16 elements)

typedef __attribute__((ext_vector_type(4))) unsigned int u32x4;
typedef __attribute__((ext_vector_type(4))) float f32x4;
typedef __attribute__((ext_vector_type(8))) short s16x8;

static __device__ __forceinline__ unsigned short f2bf(float f) {
    union { float f; unsigned int u; } v; v.f = f;
    unsigned int u = v.u;
    unsigned int r = u + 0x7FFFu + ((u >> 16) & 1u);   // RNE
    return (unsigned short)(r >> 16);
}
static __device__ __forceinline__ float bf2f(unsigned short s) {
    union { unsigned int u; float f; } v; v.u = ((unsigned int)s) << 16;
    return v.f;
}

// ---------------------------------------------------------------------------
// K-1: weight convert fp32 [ocu][180] -> bf16 [octot][192] (pads zeroed)
// ---------------------------------------------------------------------------
__global__ __launch_bounds__(256) void wconv_kernel(
    const float* __restrict__ src, unsigned short* __restrict__ dst,
    int ocu, int octot)
{
    int idx = blockIdx.x * 256 + threadIdx.x;
    if (idx >= octot * 24) return;
    int row = idx / 24, ch = idx - row * 24;
    unsigned short u[8];
#pragma unroll
    for (int e = 0; e < 8; ++e) {
        int k = ch * 8 + e;
        u[e] = (row < ocu && k < 180) ? f2bf(src[row * 180 + k]) : (unsigned short)0;
    }
    *(u32x4*)(dst + row * 192 + ch * 8) = *(const u32x4*)u;
}

// ---------------------------------------------------------------------------
// K0: transpose+cast  x fp32 [180][HW] -> xT bf16 [HW][192] (one batch)
// ---------------------------------------------------------------------------
__global__ __launch_bounds__(256) void transpose_cast_kernel(
    const float* __restrict__ x, unsigned short* __restrict__ xT)
{
    const int p0 = blockIdx.x * 64;
    const int tid = threadIdx.x;
    const int pl = tid & 63;

    __shared__ float T[180 * 65];

    for (int ic = tid >> 6; ic < 180; ic += 4)
        T[ic * 65 + pl] = x[(size_t)ic * HW + p0 + pl];
    __syncthreads();

    const int cg = tid >> 6;
    unsigned short* drow = xT + ((size_t)p0 + pl) * 192;
#pragma unroll
    for (int i = 0; i < 6; ++i) {
        int k0 = (cg * 6 + i) * 8;
        unsigned short u[8];
#pragma unroll
        for (int e = 0; e < 8; ++e)
            u[e] = (k0 + e < 180) ? f2bf(T[(k0 + e) * 65 + pl]) : (unsigned short)0;
        *(u32x4*)(drow + k0) = *(const u32x4*)u;
    }
}

// ---------------------------------------------------------------------------
// K1: qkv GEMM via MFMA (one batch). 64 oc x 256 px per block, 256 threads.
// SINGLE-buffered xs (32 KB -> ~5 blocks/CU); weights direct from wqb (L2).
// ---------------------------------------------------------------------------
__global__ __launch_bounds__(256) void gemm_qkv_kernel(
    const unsigned short* __restrict__ xT, const unsigned short* __restrict__ wqb,
    unsigned short* __restrict__ A)
{
    const int d    = blockIdx.x;               // 0..7055
    const int orig = (d & 7) * 882 + (d >> 3); // bijective (7056 = 8*882)
    const int pt   = orig / 9;
    const int ocb  = (orig - pt * 9) * 64;
    const int pix0 = pt * 256;
    const int tid  = threadIdx.x;
    const int l    = tid & 63;
    const int q    = tid >> 6;     // px quarter (64 px)
    const int r15  = l & 15;
    const int g4   = l >> 4;

    __shared__ __align__(16) unsigned short xs[256 * 64];   // 32 KiB

    auto stage = [&](int c) {
#pragma unroll
        for (int i = 0; i < 8; ++i) {
            int slot = i * 256 + tid;          // 0..2047
            int px   = slot >> 3;
            int g    = slot & 7;
            const unsigned short* src =
                xT + ((size_t)pix0 + px) * 192 + c * 64 + ((g ^ (px & 7)) << 3);
            __builtin_amdgcn_global_load_lds(
                (const __attribute__((address_space(1))) unsigned int*)(const void*)src,
                (__attribute__((address_space(3))) unsigned int*)(void*)(&xs[slot * 8]),
                16, 0, 0);
        }
    };

    f32x4 acc[4][4];   // [nt: px frag][mi: oc frag], px on reg dim
#pragma unroll
    for (int nt = 0; nt < 4; ++nt)
#pragma unroll
        for (int mi = 0; mi < 4; ++mi) acc[nt][mi] = (f32x4){0.f, 0.f, 0.f, 0.f};

    const unsigned short* wrow = wqb + (size_t)(ocb + r15) * 192;

    for (int c = 0; c < 3; ++c) {
        stage(c);
        __syncthreads();
#pragma unroll
        for (int kk = 0; kk < 2; ++kk) {
            s16x8 aX[4], bW[4];
#pragma unroll
            for (int nt = 0; nt < 4; ++nt) {
                int px = q * 64 + nt * 16 + r15;
                aX[nt] = __builtin_bit_cast(s16x8, *(const u32x4*)(
                    xs + px * 64 + (((kk * 4 + g4) ^ (px & 7)) << 3)));
            }
#pragma unroll
            for (int mi = 0; mi < 4; ++mi)
                bW[mi] = __builtin_bit_cast(s16x8, *(const u32x4*)(
                    wrow + mi * 16 * 192 + c * 64 + kk * 32 + g4 * 8));
#pragma unroll
            for (int nt = 0; nt < 4; ++nt)
#pragma unroll
                for (int mi = 0; mi < 4; ++mi)
                    acc[nt][mi] = __builtin_amdgcn_mfma_f32_16x16x32_bf16(
                        aX[nt], bW[mi], acc[nt][mi], 0, 0, 0);
        }
        if (c < 2) __syncthreads();
    }

#pragma unroll
    for (int mi = 0; mi < 4; ++mi) {
        int oc = ocb + mi * 16 + r15;
        if (oc < 540) {
            unsigned short* orow = A + (size_t)oc * HW + pix0 + q * 64 + g4 * 4;
#pragma unroll
            for (int nt = 0; nt < 4; ++nt) {
                uint2 v;
                v.x = (unsigned int)f2bf(acc[nt][mi][0]) |
                      ((unsigned int)f2bf(acc[nt][mi][1]) << 16);
                v.y = (unsigned int)f2bf(acc[nt][mi][2]) |
                      ((unsigned int)f2bf(acc[nt][mi][3]) << 16);
                *(uint2*)(orow + nt * 16) = v;
            }
        }
    }
}

// ---------------------------------------------------------------------------
// K2: depthwise 3x3 (SAME) + window rearrange (one batch).
// [R10-proposal version — best measured: 180 us] Row jobs (wo,ph) with
// even-floored float2 reads + cndmask shift; direct scattered u16 stores.
// Out: bf16 Bw [head][part][dc][win][56]  (p 49..55 zero)
// ---------------------------------------------------------------------------
__global__ __launch_bounds__(256) void dw_kernel(
    const unsigned short* __restrict__ A, const float* __restrict__ wdw,
    unsigned short* __restrict__ Bw)
{
    const int wrow = blockIdx.x;   // 0..63
    const int c    = blockIdx.y;   // 0..539
    const int tid  = threadIdx.x;

    const int part = c / 180;
    const int rem  = c - part * 180;
    const int head = rem / 30;
    const int dc   = rem - head * 30;

    __shared__ __align__(16) float Ls[9 * 454];

    float w9[9];
#pragma unroll
    for (int i = 0; i < 9; ++i) w9[i] = wdw[c * 9 + i];

    const int y0 = wrow * 7;
    const unsigned int* Ac32 = (const unsigned int*)(A + (size_t)c * HW);
    for (int idx = tid; idx < 2016; idx += 256) {
        int r  = idx / 224;
        int c2 = idx - r * 224;
        int y  = y0 + r - 1;
        unsigned int v = ((unsigned)y < 448u) ? Ac32[y * 224 + c2] : 0u;
        Ls[r * 454 + 1 + 2 * c2] = bf2f((unsigned short)(v & 0xffffu));
        Ls[r * 454 + 2 + 2 * c2] = bf2f((unsigned short)(v >> 16));
    }
    if (tid < 18) {
        int r = tid >> 1;
        Ls[r * 454 + ((tid & 1) ? 449 : 0)] = 0.f;
    }
    __syncthreads();

    unsigned short* dstb = Bw +
        ((size_t)(head * 3 + part) * 30 + dc) * VPLANE + (size_t)wrow * 3584;

    // zero pads p 49..55 for the 64 windows of this strip
    for (int idx = tid; idx < 448; idx += 256) {
        int wo = idx / 7;
        int pp = idx - wo * 7;
        dstb[wo * 56 + 49 + pp] = 0;
    }

    // row jobs: job = wo*7 + ph; needs Ls cols wo*7 .. wo*7+8, rows ph..ph+2
#pragma unroll
    for (int it = 0; it < 2; ++it) {
        int job = it * 256 + tid;
        if (job < 448) {
            int wo  = job / 7;
            int ph  = job - wo * 7;
            int base = wo * 7;
            int s    = base & ~1;          // even floor
            int dlt  = base & 1;

            float v[3][9];                 // shifted window: v[k][j] = Ls[row][base+j]
#pragma unroll
            for (int k = 0; k < 3; ++k) {
                const float2* Lp = (const float2*)(Ls + (ph + k) * 454 + s);
                float2 a0 = Lp[0], a1 = Lp[1], a2 = Lp[2], a3 = Lp[3], a4 = Lp[4];
                float t0 = a0.x, t1 = a0.y, t2 = a1.x, t3 = a1.y, t4 = a2.x,
                      t5 = a2.y, t6 = a3.x, t7 = a3.y, t8 = a4.x, t9 = a4.y;
                v[k][0] = dlt ? t1 : t0;
                v[k][1] = dlt ? t2 : t1;
                v[k][2] = dlt ? t3 : t2;
                v[k][3] = dlt ? t4 : t3;
                v[k][4] = dlt ? t5 : t4;
                v[k][5] = dlt ? t6 : t5;
                v[k][6] = dlt ? t7 : t6;
                v[k][7] = dlt ? t8 : t7;
                v[k][8] = dlt ? t9 : t8;
            }

            unsigned short* orow = dstb + wo * 56 + ph * 7;
#pragma unroll
            for (int pw = 0; pw < 7; ++pw) {
                float acc = w9[0]*v[0][pw] + w9[1]*v[0][pw+1] + w9[2]*v[0][pw+2]
                          + w9[3]*v[1][pw] + w9[4]*v[1][pw+1] + w9[5]*v[1][pw+2]
                          + w9[6]*v[2][pw] + w9[7]*v[2][pw+1] + w9[8]*v[2][pw+2];
                orow[pw] = f2bf(acc);
            }
        }
    }
}

// ---------------------------------------------------------------------------
// K3: channel attention (one batch). Block = 4 consecutive windows of one head,
// one wave each. Vectorized b128 staging for Q/K; per-element transpose for V.
// Out: Cwt [win][49][192] bf16 (ch 180..191 zeroed by head==5)
// ---------------------------------------------------------------------------
__global__ __launch_bounds__(256) void attn2_kernel(
    const unsigned short* __restrict__ Bw,
    const float* __restrict__ temperature,
    unsigned short* __restrict__ Cwt)
{
    __shared__ __align__(16) unsigned short lds[4][6144];
    __shared__ float invs[4][64];

    const int w    = threadIdx.x >> 6;
    const int l    = threadIdx.x & 63;
    const int wg   = blockIdx.x;
    const int head = blockIdx.y;
    const int win  = wg * 4 + w;
    const float temp = temperature[head];
    unsigned short* U = lds[w];
    float* inv = invs[w];
    const int r15 = l & 15;
    const int g4  = l >> 4;

    // ---- stage Q/K: 8 b128 per lane (rows>=30 and chunk 7 -> zeros) ----
    {
        const unsigned short* plane0 =
            Bw + (size_t)(head * 3) * 30 * VPLANE + (size_t)win * 56;
#pragma unroll
        for (int i = 0; i < 8; ++i) {
            int part = i >> 2;
            int row  = ((i & 3) << 3) | (l >> 3);   // 0..31
            int c    = l & 7;
            u32x4 v = {0u, 0u, 0u, 0u};
            if (row < 30 && c < 7)
                v = *(const u32x4*)(plane0 + (size_t)(part * 30 + row) * VPLANE + c * 8);
            *(u32x4*)(U + part * 2048 + row * 64 + ((c ^ (row & 7)) << 3)) = v;
        }
    }
    // ---- stage V transposed into Vt [p][32] (swizzled), zero cols 30/31 ----
    {
        const unsigned short* vplane =
            Bw + (size_t)(head * 3 + 2) * 30 * VPLANE + (size_t)win * 56;
        for (int j = 0; j < 23; ++j) {
            int idx = j * 64 + l;
            if (idx < 1470) {
                int dc = idx / 49;
                int p  = idx - dc * 49;
                unsigned short val = vplane[(size_t)dc * VPLANE + p];
                int col = (((dc >> 3) ^ (p & 3)) << 3) | (dc & 7);
                U[4096 + p * 32 + col] = val;
            }
        }
        int c30 = ((3 ^ (l & 3)) << 3) | 6;         // dc=30 slot for p=l
        U[4096 + l * 32 + c30]     = 0;
        U[4096 + l * 32 + c30 + 1] = 0;             // dc=31
    }
    __syncthreads();

    s16x8 aQ[2][2], bK[2][2];
#pragma unroll
    for (int mi = 0; mi < 2; ++mi)
#pragma unroll
        for (int kk = 0; kk < 2; ++kk) {
            int r  = mi * 16 + r15;
            int gk = kk * 4 + g4;
            int so = ((gk ^ (r & 7)) << 3);
            aQ[mi][kk] = __builtin_bit_cast(s16x8, *(const u32x4*)(U + r * 64 + so));
            bK[mi][kk] = __builtin_bit_cast(s16x8, *(const u32x4*)(U + 2048 + r * 64 + so));
        }

    f32x4 s[2][2], dq[2], dk[2];
#pragma unroll
    for (int mi = 0; mi < 2; ++mi) {
        dq[mi] = (f32x4){0.f, 0.f, 0.f, 0.f};
        dk[mi] = (f32x4){0.f, 0.f, 0.f, 0.f};
#pragma unroll
        for (int nj = 0; nj < 2; ++nj) s[mi][nj] = (f32x4){0.f, 0.f, 0.f, 0.f};
    }

#pragma unroll
    for (int kk = 0; kk < 2; ++kk) {
#pragma unroll
        for (int mi = 0; mi < 2; ++mi) {
#pragma unroll
            for (int nj = 0; nj < 2; ++nj)
                s[mi][nj] = __builtin_amdgcn_mfma_f32_16x16x32_bf16(
                    aQ[mi][kk], bK[nj][kk], s[mi][nj], 0, 0, 0);
            dq[mi] = __builtin_amdgcn_mfma_f32_16x16x32_bf16(
                aQ[mi][kk], aQ[mi][kk], dq[mi], 0, 0, 0);
            dk[mi] = __builtin_amdgcn_mfma_f32_16x16x32_bf16(
                bK[mi][kk], bK[mi][kk], dk[mi], 0, 0, 0);
        }
    }

#pragma unroll
    for (int mi = 0; mi < 2; ++mi)
#pragma unroll
        for (int reg = 0; reg < 4; ++reg) {
            int row = g4 * 4 + reg;
            if (row == r15) {
                inv[mi * 16 + row]      = 1.f / fmaxf(sqrtf(dq[mi][reg]), 1e-12f);
                inv[32 + mi * 16 + row] = 1.f / fmaxf(sqrtf(dk[mi][reg]), 1e-12f);
            }
        }
    __syncthreads();

    float pr[2][2][4];
    float cinvk0 = inv[32 + r15];
    float cinvk1 = inv[32 + 16 + r15];
#pragma unroll
    for (int mi = 0; mi < 2; ++mi)
#pragma unroll
        for (int reg = 0; reg < 4; ++reg) {
            float qi = inv[mi * 16 + g4 * 4 + reg];
            float v0 = s[mi][0][reg] * qi * cinvk0 * temp;
            float v1 = s[mi][1][reg] * qi * cinvk1 * temp;
            if (16 + r15 >= 30) v1 = -1e30f;
            float m = fmaxf(v0, v1);
#pragma unroll
            for (int off = 1; off < 16; off <<= 1) m = fmaxf(m, __shfl_xor(m, off));
            float e0 = __expf(v0 - m);
            float e1 = __expf(v1 - m);
            float sum = e0 + e1;
#pragma unroll
            for (int off = 1; off < 16; off <<= 1) sum += __shfl_xor(sum, off);
            float rs = 1.f / sum;
            pr[mi][0][reg] = e0 * rs;
            pr[mi][1][reg] = e1 * rs;
        }

#pragma unroll
    for (int mi = 0; mi < 2; ++mi)
#pragma unroll
        for (int nj = 0; nj < 2; ++nj)
#pragma unroll
            for (int reg = 0; reg < 4; ++reg) {
                int row = mi * 16 + g4 * 4 + reg;
                int col = nj * 16 + r15;
                int scol = (((col >> 3) ^ (row & 3)) << 3) | (col & 7);
                U[row * 32 + scol] = f2bf(pr[mi][nj][reg]);
            }
    __syncthreads();

    s16x8 aP[2], bV[4];
#pragma unroll
    for (int mi = 0; mi < 2; ++mi) {
        int i = mi * 16 + r15;
        aP[mi] = __builtin_bit_cast(s16x8,
                 *(const u32x4*)(U + i * 32 + ((g4 ^ (i & 3)) << 3)));
    }
#pragma unroll
    for (int nt = 0; nt < 4; ++nt) {
        int p = nt * 16 + r15;
        bV[nt] = __builtin_bit_cast(s16x8,
                 *(const u32x4*)(U + 4096 + p * 32 + ((g4 ^ (p & 3)) << 3)));
    }
    f32x4 o[2][4];
#pragma unroll
    for (int mi = 0; mi < 2; ++mi)
#pragma unroll
        for (int nt = 0; nt < 4; ++nt) {
            o[mi][nt] = (f32x4){0.f, 0.f, 0.f, 0.f};
            o[mi][nt] = __builtin_amdgcn_mfma_f32_16x16x32_bf16(
                aP[mi], bV[nt], o[mi][nt], 0, 0, 0);
        }

    unsigned short* dst = Cwt + ((size_t)win * 49) * 192 + head * 30;
#pragma unroll
    for (int mi = 0; mi < 2; ++mi) {
        int ch0 = mi * 16 + g4 * 4;
#pragma unroll
        for (int nt = 0; nt < 4; ++nt) {
            int p = nt * 16 + r15;
            if (p < 49) {
                unsigned int lo = (unsigned int)f2bf(o[mi][nt][0]) |
                                  ((unsigned int)f2bf(o[mi][nt][1]) << 16);
                *(unsigned int*)(dst + (size_t)p * 192 + ch0) = lo;
                if (ch0 + 2 < 30) {
                    unsigned int hi = (unsigned int)f2bf(o[mi][nt][2]) |
                                      ((unsigned int)f2bf(o[mi][nt][3]) << 16);
                    *(unsigned int*)(dst + (size_t)p * 192 + ch0 + 2) = hi;
                }
            }
        }
    }
    if (head == 5 && g4 == 0) {
        unsigned short* zrow = Cwt + ((size_t)win * 49) * 192 + 180;
#pragma unroll
        for (int nt = 0; nt < 4; ++nt) {
            int p = nt * 16 + r15;
            if (p < 49) {
                *(unsigned int*)(zrow + (size_t)p * 192 + 0) = 0u;
                *(unsigned int*)(zrow + (size_t)p * 192 + 2) = 0u;
                *(unsigned int*)(zrow + (size_t)p * 192 + 4) = 0u;
            }
        }
    }
}

// ---------------------------------------------------------------------------
// K4: proj GEMM via MFMA (one batch). SINGLE-buffered xs (32 KB).
// ---------------------------------------------------------------------------
__global__ __launch_bounds__(256) void gemm_proj_kernel(
    const unsigned short* __restrict__ Cwt, const unsigned short* __restrict__ wpb,
    float* __restrict__ out)
{
    const int d    = blockIdx.x;                 // 0..2351
    const int orig = (d & 7) * 294 + (d >> 3);   // bijective (2352 = 8*294)
    const int pt   = orig / 3;
    const int ocb  = (orig - pt * 3) * 64;
    const int pix0 = pt * 256;
    const int tid  = threadIdx.x;
    const int l    = tid & 63;
    const int q    = tid >> 6;     // px quarter (64 px)
    const int r15  = l & 15;
    const int g4   = l >> 4;

    __shared__ __align__(16) unsigned short xs[256 * 64];   // 32 KiB

    auto stage = [&](int c) {
#pragma unroll
        for (int i = 0; i < 8; ++i) {
            int slot = i * 256 + tid;          // 0..2047
            int px   = slot >> 3;
            int g    = slot & 7;
            const unsigned short* src =
                Cwt + ((size_t)pix0 + px) * 192 + c * 64 + ((g ^ (px & 7)) << 3);
            __builtin_amdgcn_global_load_lds(
                (const __attribute__((address_space(1))) unsigned int*)(const void*)src,
                (__attribute__((address_space(3))) unsigned int*)(void*)(&xs[slot * 8]),
                16, 0, 0);
        }
    };

    f32x4 acc[4][4];   // [mi: oc frag][nt: px frag], D col = px
#pragma unroll
    for (int mi = 0; mi < 4; ++mi)
#pragma unroll
        for (int nt = 0; nt < 4; ++nt) acc[mi][nt] = (f32x4){0.f, 0.f, 0.f, 0.f};

    const unsigned short* wrow = wpb + (size_t)(ocb + r15) * 192;

    for (int c = 0; c < 3; ++c) {
        stage(c);
        __syncthreads();
#pragma unroll
        for (int kk = 0; kk < 2; ++kk) {
            s16x8 aW[4], bX[4];
#pragma unroll
            for (int mi = 0; mi < 4; ++mi)
                aW[mi] = __builtin_bit_cast(s16x8, *(const u32x4*)(
                    wrow + mi * 16 * 192 + c * 64 + kk * 32 + g4 * 8));
#pragma unroll
            for (int nt = 0; nt < 4; ++nt) {
                int px = q * 64 + nt * 16 + r15;
                bX[nt] = __builtin_bit_cast(s16x8, *(const u32x4*)(
                    xs + px * 64 + (((kk * 4 + g4) ^ (px & 7)) << 3)));
            }
#pragma unroll
            for (int mi = 0; mi < 4; ++mi)
#pragma unroll
                for (int nt = 0; nt < 4; ++nt)
                    acc[mi][nt] = __builtin_amdgcn_mfma_f32_16x16x32_bf16(
                        aW[mi], bX[nt], acc[mi][nt], 0, 0, 0);
        }
        if (c < 2) __syncthreads();
    }

    int poff[4];
#pragma unroll
    for (int nt = 0; nt < 4; ++nt) {
        int P = pix0 + q * 64 + nt * 16 + r15;
        int win = P / 49, p = P - win * 49;
        int ph = p / 7, pw2 = p - ph * 7;
        poff[nt] = ((win >> 6) * 7 + ph) * WIMG + (win & 63) * 7 + pw2;
    }
#pragma unroll
    for (int mi = 0; mi < 4; ++mi) {
#pragma unroll
        for (int reg = 0; reg < 4; ++reg) {
            int oc = ocb + mi * 16 + g4 * 4 + reg;
            if (oc < 180) {
#pragma unroll
                for (int nt = 0; nt < 4; ++nt)
                    out[(size_t)oc * HW + poff[nt]] = acc[mi][nt][reg];
            }
        }
    }
}

extern "C" void kernel_launch(void* const* d_in, const int* in_sizes, int n_in,
                              void* d_out, int out_size, void* d_ws, size_t ws_size,
                              hipStream_t stream) {
    const float* x           = (const float*)d_in[0];
    const float* temperature = (const float*)d_in[1];
    const float* w_qkv       = (const float*)d_in[2];
    const float* w_dw        = (const float*)d_in[3];
    const float* w_proj      = (const float*)d_in[4];
    float* out = (float*)d_out;

    // per-batch buffers (reused for b=0,1):
    // xT  @ 0          :  77,070,336 B
    // A   @ 77070336   : 216,760,320 B
    // Bw  @ 293830656  : 247,726,080 B
    // Cwt @ 541556736  :  77,070,336 B
    // wqb @ 618627072  :     221,184 B
    // wpb @ 618848256  :      73,728 B
    if (ws_size < 618921984ull) return;
    unsigned short* xT  = (unsigned short*)d_ws;
    unsigned short* A   = (unsigned short*)((char*)d_ws + 77070336ull);
    unsigned short* Bw  = (unsigned short*)((char*)d_ws + 293830656ull);
    unsigned short* Cwt = (unsigned short*)((char*)d_ws + 541556736ull);
    unsigned short* wqb = (unsigned short*)((char*)d_ws + 618627072ull);
    unsigned short* wpb = (unsigned short*)((char*)d_ws + 618848256ull);

    wconv_kernel<<<dim3(54), 256, 0, stream>>>(w_qkv, wqb, 540, 576);
    wconv_kernel<<<dim3(18), 256, 0, stream>>>(w_proj, wpb, 180, 192);

    for (int b = 0; b < 2; ++b) {
        const float* xb = x + (size_t)b * 180 * HW;
        float* ob = out + (size_t)b * 180 * HW;
        transpose_cast_kernel<<<dim3(HW / 64), 256, 0, stream>>>(xb, xT);
        gemm_qkv_kernel<<<dim3(7056), 256, 0, stream>>>(xT, wqb, A);
        dw_kernel<<<dim3(64, 540), 256, 0, stream>>>(A, w_dw, Bw);
        attn2_kernel<<<dim3(1024, 6), 256, 0, stream>>>(Bw, temperature, Cwt);
        gemm_proj_kernel<<<dim3(2352), 256, 0, stream>>>(Cwt, wpb, ob);
    }
}